// Round 18
// baseline (5267.726 us; speedup 1.0000x reference)
//
#include <hip/hip_runtime.h>
#include <math.h>

typedef __attribute__((ext_vector_type(8))) short v8s;
typedef __attribute__((ext_vector_type(2))) short v2s;
typedef __attribute__((ext_vector_type(4))) float v4f;

#define AP 136              // padded LDS row stride (shorts); 272 B rows keep 16B align
#define OFF_W3 0
#define OFF_WI 524288
#define OFF_W1 528384
#define OFF_W2 544768
#define OFF_WR 561152
#define LO     565248       // lo-residual region offset (shorts)
#define WF_TOTAL2 1130496   // hi+lo regions (shorts, 2.26 MB)
#define KBUF_BYTE 2260992   // float kbuf[16 bg][2 par][2048]  (256 KB)
#define FLG_BYTE  2523136   // uint flags[16 bg][16 tr] @ 16 B spacing (4 KB)
#define WS_END    2527232
#define PREP_W    565248    // weight-shuffle thread count
#define PREP_Z    33280     // zeroing threads: [KBUF_BYTE, WS_END) / 8
#define PREP_TOT  598528

static __device__ __forceinline__ float bf2f(unsigned short s){
    union { unsigned u; float f; } v; v.u = ((unsigned)s) << 16; return v.f;
}
static __device__ __forceinline__ unsigned short f2bf(float f){
    union { float ff; unsigned u; } v; v.ff = f;
    return (unsigned short)((v.u + 0x7FFFu + ((v.u >> 16) & 1u)) >> 16);
}
// triple split: v = h + m + l + eps, |eps| <= 2^-27 |v|
static __device__ __forceinline__ void split3(float v, unsigned short& h,
                                              unsigned short& m, unsigned short& l){
    h = f2bf(v);  float r1 = v - bf2f(h);
    m = f2bf(r1); float r2 = r1 - bf2f(m);
    l = f2bf(r2);
}
static __device__ __forceinline__ float softplus_f(float x){
    float t = __builtin_amdgcn_exp2f(x * 1.44269504088896341f);
    float r = 0.69314718055994531f * __builtin_amdgcn_logf(1.0f + t);
    return (x > 20.0f) ? x : r;
}
static __device__ __forceinline__ float tanh_f(float x){
    float xc = fminf(fmaxf(x, -9.0f), 9.0f);
    float t = __builtin_amdgcn_exp2f(xc * 2.8853900817779268f); // e^{2x}
    float d = t + 1.0f;
    float r = __builtin_amdgcn_rcpf(d);
    r = r * (2.0f - d * r);                                     // NR refine
    return (t - 1.0f) * r;
}

#define MFMA(acc, a, b) acc = __builtin_amdgcn_mfma_f32_16x16x32_bf16(a, b, acc, 0, 0, 0)

// ---------------------------------------------------------------------------
// Merged prep: fp32 weights -> bf16 hi+lo B-fragment layout, + zero the
// exchange region [KBUF_BYTE, WS_END).
// frag elem = W[kt*32 + (lane>>4)*8 + j][nt*16 + (lane&15)]
// ---------------------------------------------------------------------------
__global__ void prep_kernel(const float* __restrict__ W3,
                            const float* __restrict__ Wi,
                            const float* __restrict__ W1,
                            const float* __restrict__ W2,
                            const float* __restrict__ Wr,
                            unsigned short* __restrict__ dst,
                            int wlimit, unsigned long long wsbytes){
    int g = blockIdx.x * 256 + threadIdx.x;
    if (g >= PREP_TOT) return;
    if (g >= PREP_W){
        int t = g - PREP_W;
        unsigned long long byte = (unsigned long long)KBUF_BYTE + (unsigned long long)t * 8ull;
        if (t < PREP_Z && byte + 8ull <= wsbytes)
            *(unsigned long long*)((char*)dst + byte) = 0ull;
        return;
    }

    const float* W; int KT, N, t;
    if      (g < OFF_WI){ W = W3; KT = 4; N = 4096; t = g; }
    else if (g < OFF_W1){ W = Wi; KT = 1; N = 128;  t = g - OFF_WI; }
    else if (g < OFF_W2){ W = W1; KT = 4; N = 128;  t = g - OFF_W1; }
    else if (g < OFF_WR){ W = W2; KT = 4; N = 128;  t = g - OFF_W2; }
    else               { W = Wr; KT = 4; N = 32;   t = g - OFF_WR; }

    int j  = t & 7;
    int l  = (t >> 3) & 63;
    int t2 = t >> 9;
    int kt = t2 % KT;
    int nt = t2 / KT;
    int row = kt * 32 + (l >> 4) * 8 + j;
    int col = nt * 16 + (l & 15);
    float w = W[(size_t)row * N + col];
    unsigned short h = f2bf(w);
    if (g < wlimit)      dst[g]      = h;
    if (g + LO < wlimit) dst[g + LO] = f2bf(w - bf2f(h));
}

// ---------------------------------------------------------------------------
// Single-tile 5-MFMA split GEMM, r-split across wave halves:
// waves w and w+8 BOTH compute tile nt = w&7's full accumulator (duplicated
// MFMA, bit-identical); wave w handles acc rows r in {0,1}, wave w+8 handles
// r in {2,3}. Epilogue serial chain per wave halves.
// MODE 0: +bias -> zx[16x128]   MODE 1: +bias, softplus -> triple A-out
// MODE 4: +bias +x_last -> out fp32 global
// ---------------------------------------------------------------------------
template<int KT, int MODE>
static __device__ __forceinline__ void gemm1(
    const unsigned short* __restrict__ wf, int wbase, int ntiles,
    const unsigned short* Ah, const unsigned short* Am, const unsigned short* Al,
    unsigned short* Aoh, unsigned short* Aom, unsigned short* Aol,
    float* zx,
    const float* __restrict__ bias_g,
    const float* __restrict__ xlast, float* __restrict__ outg, int bg)
{
    const int tid  = threadIdx.x;
    const int lane = tid & 63;
    const int wid  = tid >> 6;
    const int l15  = lane & 15;
    const int q    = lane >> 4;
    const int nt   = wid & 7;
    const int rlo  = (wid >> 3) * 2;
    if (nt >= ntiles) return;

    v8s ah[KT], am[KT], al[KT];
#pragma unroll
    for (int kt = 0; kt < KT; ++kt){
        ah[kt] = *(const v8s*)&Ah[l15 * AP + kt * 32 + q * 8];
        am[kt] = *(const v8s*)&Am[l15 * AP + kt * 32 + q * 8];
        al[kt] = *(const v8s*)&Al[l15 * AP + kt * 32 + q * 8];
    }

    v4f acc = {0.f, 0.f, 0.f, 0.f};
#pragma unroll
    for (int kt = 0; kt < KT; ++kt){
        int o = wbase + ((nt * KT + kt) * 64 + lane) * 8;
        v8s bh = *(const v8s*)&wf[o];
        v8s bl = *(const v8s*)&wf[o + LO];
        MFMA(acc, ah[kt], bh); MFMA(acc, am[kt], bh); MFMA(acc, al[kt], bh);
        MFMA(acc, ah[kt], bl); MFMA(acc, am[kt], bl);
    }
    const int c0 = nt * 16 + l15;

    if (MODE == 0){
#pragma unroll
        for (int rr = 0; rr < 2; ++rr){
            int r = rlo + rr, b = q * 4 + r;
            zx[b * 128 + c0] = acc[r] + bias_g[c0];
        }
    } else if (MODE == 1){
#pragma unroll
        for (int rr = 0; rr < 2; ++rr){
            int r = rlo + rr, b = q * 4 + r;
            float v0 = softplus_f(acc[r] + bias_g[c0]);
            unsigned short h, m, l;
            split3(v0, h, m, l);
            Aoh[b*AP+c0] = h; Aom[b*AP+c0] = m; Aol[b*AP+c0] = l;
        }
    } else { // MODE 4
#pragma unroll
        for (int rr = 0; rr < 2; ++rr){
            int r = rlo + rr, b = q * 4 + r, gb = bg * 16 + b;
            outg[gb * 32 + c0] = acc[r] + bias_g[c0] + xlast[gb * 32 + c0];
        }
    }
}

// ---------------------------------------------------------------------------
// Persistent team kernel: 256 blocks x 1024 threads (16 waves = 4 waves/EU).
// __launch_bounds__(1024, 4) -> VGPR cap 128 (r16 proved the per-wave
// structure fits in 112; r17's default cap of 64 caused the 11 GB spill).
// Wave pair (w, w+8) duplicates MFMA on tile/pair w&7 and r-splits the
// epilogue. Exchange: relaxed stores -> vmcnt(0)/wave -> barrier -> one
// block flag; consumer thread polls only ITS producer ((tid&63)>>2).
// ---------------------------------------------------------------------------
__global__ __launch_bounds__(1024, 4) void cde_kernel(
    const float* __restrict__ coeffs,
    const float* __restrict__ x_last,
    const float* __restrict__ bi,
    const float* __restrict__ b1,
    const float* __restrict__ b2,
    const float* __restrict__ b3,
    const float* __restrict__ br,
    const unsigned short* __restrict__ wf,
    float* __restrict__ kbuf,
    unsigned int* __restrict__ flgs,
    float* __restrict__ outg)
{
    __shared__ unsigned short A0h[16*AP] __attribute__((aligned(16)));
    __shared__ unsigned short A0m[16*AP] __attribute__((aligned(16)));
    __shared__ unsigned short A0l[16*AP] __attribute__((aligned(16)));
    __shared__ unsigned short A1h[16*AP] __attribute__((aligned(16)));
    __shared__ unsigned short A1m[16*AP] __attribute__((aligned(16)));
    __shared__ unsigned short A1l[16*AP] __attribute__((aligned(16)));
    __shared__ unsigned short A2h[16*AP] __attribute__((aligned(16)));
    __shared__ unsigned short A2m[16*AP] __attribute__((aligned(16)));
    __shared__ unsigned short A2l[16*AP] __attribute__((aligned(16)));
    __shared__ float dval[512];
    __shared__ float zx[2048];

    const int tid  = threadIdx.x;
    const int lane = tid & 63;
    const int wid  = tid >> 6;          // 0..15
    const int l15  = lane & 15;
    const int q    = lane >> 4;
    const int wid8 = wid & 7;
    const int rlo  = (wid >> 3) * 2;
    const int bx   = blockIdx.x;
    const int bg   = (bx & 7) * 2 + (bx >> 7);   // team members share bx%8 (XCD)
    const int tr   = (bx >> 3) & 15;

    float*        kb0     = kbuf + bg * 4096;    // [par][2048]
    unsigned int* teamflg = flgs + bg * 64;      // 16 block flags @ 16 B
    unsigned int* myflag  = teamflg + tr * 4;

    for (int e = tid; e < 16*AP; e += 1024){
        A0h[e]=0; A0m[e]=0; A0l[e]=0; A1h[e]=0; A1m[e]=0; A1l[e]=0;
        A2h[e]=0; A2m[e]=0; A2l[e]=0;
    }

    // reg-cached W3 slice frags; wave pair (w, w+8) shares pair p = wid8
    v8s w3h[2][4], w3l[2][4];   // [tile-in-pair][kt]
    float b3v[2];
    {
        const int p = wid8;
#pragma unroll
        for (int i = 0; i < 2; ++i){
            int ntg = tr * 16 + 2 * p + i;
#pragma unroll
            for (int kt = 0; kt < 4; ++kt){
                int o = ((ntg * 4 + kt) * 64 + lane) * 8;   // OFF_W3 = 0
                w3h[i][kt] = *(const v8s*)&wf[o];
                w3l[i][kt] = *(const v8s*)&wf[o + LO];
            }
        }
        int cg0 = tr * 256 + p * 32 + l15;
        b3v[0] = b3[cg0]; b3v[1] = b3[cg0 + 16];
    }

    const int arow = tid >> 6;          // staging row 0..15 (tid*2 elems)
    const int acol = (tid & 63) * 2;
    const int e0r  = (tid >> 5) & 15, e0c = tid & 31;   // dval elem (tid<512)

    // prologue: z0 = a0 @ Wi + bi
    if (tid < 512){
        float v = coeffs[((size_t)(bg * 16 + e0r) * 64) * 128 + e0c];
        unsigned short h, m, l; split3(v, h, m, l);
        A0h[e0r*AP+e0c] = h; A0m[e0r*AP+e0c] = m; A0l[e0r*AP+e0c] = l;
    }
    __syncthreads();
    gemm1<1, 0>(wf, OFF_WI, 8, A0h, A0m, A0l, nullptr, nullptr, nullptr,
                zx, bi, nullptr, nullptr, bg);
    __syncthreads();

    // thread-private RK4 state: thread owns elems e = tid*2, tid*2+1
    float zp[2], kap[2], k1p[2], k2p[2];
#pragma unroll
    for (int i = 0; i < 2; ++i){ zp[i] = zx[tid*2 + i]; kap[i]=0.f; k1p[i]=0.f; k2p[i]=0.f; }

    // pre-loop: dval(0) + A0 stage for stage 0 (sub=0 -> from zp)
    {
        if (tid < 512){
            size_t base = ((size_t)(bg * 16 + e0r) * 64 + 0) * 128;
            dval[tid] = coeffs[base + 32 + e0c];
        }
        v2s vh, vm, vl;
#pragma unroll
        for (int i = 0; i < 2; ++i){
            unsigned short h, m, l; split3(zp[i], h, m, l);
            vh[i] = (short)h; vm[i] = (short)m; vl[i] = (short)l;
        }
        *(v2s*)&A0h[arow*AP + acol] = vh;
        *(v2s*)&A0m[arow*AP + acol] = vm;
        *(v2s*)&A0l[arow*AP + acol] = vl;
    }

    for (int st = 0; st < 256; ++st){
        const int sub = st & 3;
        __syncthreads();                       // (1) A0 + dval visible
        gemm1<4, 1>(wf, OFF_W1, 8, A0h, A0m, A0l, A1h, A1m, A1l,
                    nullptr, b1, nullptr, nullptr, bg);
        __syncthreads();                       // (2)
        gemm1<4, 1>(wf, OFF_W2, 8, A1h, A1m, A1l, A2h, A2m, A2l,
                    nullptr, b2, nullptr, nullptr, bg);
        __syncthreads();                       // (3)
        float* kbw = kb0 + (st & 1) * 2048;
        {   // W3 pair (reg frags) -> k column h = tr*8 + wid8; r-split halves
            v8s ah[4], am[4], al[4];
#pragma unroll
            for (int kt = 0; kt < 4; ++kt){
                ah[kt] = *(const v8s*)&A2h[l15*AP + kt*32 + q*8];
                am[kt] = *(const v8s*)&A2m[l15*AP + kt*32 + q*8];
                al[kt] = *(const v8s*)&A2l[l15*AP + kt*32 + q*8];
            }
            v4f acc0 = {0.f,0.f,0.f,0.f}, acc1 = {0.f,0.f,0.f,0.f};
#pragma unroll
            for (int kt = 0; kt < 4; ++kt){
                MFMA(acc0, ah[kt], w3h[0][kt]); MFMA(acc0, am[kt], w3h[0][kt]);
                MFMA(acc0, al[kt], w3h[0][kt]);
                MFMA(acc0, ah[kt], w3l[0][kt]); MFMA(acc0, am[kt], w3l[0][kt]);
                MFMA(acc1, ah[kt], w3h[1][kt]); MFMA(acc1, am[kt], w3h[1][kt]);
                MFMA(acc1, al[kt], w3h[1][kt]);
                MFMA(acc1, ah[kt], w3l[1][kt]); MFMA(acc1, am[kt], w3l[1][kt]);
            }
            float s4[2];
#pragma unroll
            for (int rr = 0; rr < 2; ++rr){
                int r = rlo + rr;
                float u0 = acc0[r] + b3v[0];
                float u1 = acc1[r] + b3v[1];
                s4[rr] = tanh_f(u0) * dval[(q*4 + r) * 32 + l15]
                       + tanh_f(u1) * dval[(q*4 + r) * 32 + 16 + l15];
            }
#pragma unroll
            for (int sm = 1; sm <= 8; sm <<= 1){
#pragma unroll
                for (int rr = 0; rr < 2; ++rr) s4[rr] += __shfl_xor(s4[rr], sm);
            }
            if (l15 == 0){
#pragma unroll
                for (int rr = 0; rr < 2; ++rr){
                    int r = rlo + rr;
                    __hip_atomic_store(&kbw[(q*4 + r) * 128 + tr * 8 + wid8], s4[rr],
                                       __ATOMIC_RELAXED, __HIP_MEMORY_SCOPE_AGENT);
                }
            }
            // publish: each wave drains its stores; barrier; one block flag
            asm volatile("s_waitcnt vmcnt(0)" ::: "memory");
            __syncthreads();
            if (tid == 0)
                __hip_atomic_store(myflag, (unsigned)(st + 1),
                                   __ATOMIC_RELAXED, __HIP_MEMORY_SCOPE_AGENT);
        }

        // prefetch next stage's spline coeffs into registers (hides wait)
        const int stp1 = (st < 255) ? st + 1 : 255;
        const int sp   = stp1 >> 2, sb = stp1 & 3;
        int nidx; float nfrac;
        if      (sb == 0){ nidx = sp; nfrac = 0.f; }
        else if (sb == 1){ nidx = sp; nfrac = 1.f / 3.f; }
        else if (sb == 2){ nidx = sp; nfrac = 2.f / 3.f; }
        else { nidx = (sp < 63) ? sp + 1 : 63; nfrac = (sp < 63) ? 0.f : 1.f; }
        float cb0 = 0.f, cc0 = 0.f, cd0 = 0.f;
        if (tid < 512){
            size_t base = ((size_t)(bg * 16 + e0r) * 64 + nidx) * 128;
            cb0 = coeffs[base + 32 + e0c];
            cc0 = coeffs[base + 64 + e0c];
            cd0 = coeffs[base + 96 + e0c];
        }

        // per-thread wait: only this thread's producer ((tid&63)>>2)
        {
            const unsigned tgt = (unsigned)(st + 1);
            const unsigned int* fp = &teamflg[((tid & 63) >> 2) * 4];
            unsigned it = 0;
            while (__hip_atomic_load(fp, __ATOMIC_RELAXED,
                                     __HIP_MEMORY_SCOPE_AGENT) < tgt
                   && ++it < (1u << 22))
                __builtin_amdgcn_s_sleep(1);
        }

        // one 8B packed relaxed kv load
        float kv[2];
        {
            union { unsigned long long u; float f[2]; } pk;
            pk.u = __hip_atomic_load((const unsigned long long*)&kbw[tid*2],
                                     __ATOMIC_RELAXED, __HIP_MEMORY_SCOPE_AGENT);
            kv[0] = pk.f[0]; kv[1] = pk.f[1];
        }
#pragma unroll
        for (int i = 0; i < 2; ++i){
            float k = kv[i];
            if      (sub == 0){ k1p[i] = k; kap[i] = zp[i] + k * (1.f/3.f); }
            else if (sub == 1){ k2p[i] = k; kap[i] = zp[i] + (k - k1p[i] * (1.f/3.f)); }
            else if (sub == 2){ kap[i] = zp[i] + (k1p[i] - k2p[i] + k); }
            else { zp[i] = zp[i] + (6.f*k2p[i] - 2.f*k1p[i]
                                    + 3.f*(kap[i] - zp[i]) + k) * 0.125f; }
        }

        // dval(s+1) + A0 stage for s+1 (no barrier needed until (1))
        if (tid < 512)
            dval[tid] = cb0 + (cc0 + cd0 * nfrac) * nfrac;
        {
            const int nsub = stp1 & 3;
            v2s vh, vm, vl;
#pragma unroll
            for (int i = 0; i < 2; ++i){
                float v = (nsub == 0) ? zp[i] : kap[i];
                unsigned short h, m, l; split3(v, h, m, l);
                vh[i] = (short)h; vm[i] = (short)m; vl[i] = (short)l;
            }
            *(v2s*)&A0h[arow*AP + acol] = vh;
            *(v2s*)&A0m[arow*AP + acol] = vm;
            *(v2s*)&A0l[arow*AP + acol] = vl;
        }
    }

    // epilogue: out = x_last + z @ Wr + br  (team blocks write identical values)
    {
        v2s vh, vm, vl;
#pragma unroll
        for (int i = 0; i < 2; ++i){
            unsigned short h, m, l; split3(zp[i], h, m, l);
            vh[i] = (short)h; vm[i] = (short)m; vl[i] = (short)l;
        }
        *(v2s*)&A0h[arow*AP + acol] = vh;
        *(v2s*)&A0m[arow*AP + acol] = vm;
        *(v2s*)&A0l[arow*AP + acol] = vl;
    }
    __syncthreads();
    gemm1<4, 4>(wf, OFF_WR, 2, A0h, A0m, A0l, nullptr, nullptr, nullptr,
                nullptr, br, x_last, outg, bg);
}

extern "C" void kernel_launch(void* const* d_in, const int* in_sizes, int n_in,
                              void* d_out, int out_size, void* d_ws, size_t ws_size,
                              hipStream_t stream)
{
    const float* coeffs = (const float*)d_in[0];
    const float* x_last = (const float*)d_in[1];
    const float* Wi     = (const float*)d_in[2];
    const float* bi     = (const float*)d_in[3];
    const float* W1     = (const float*)d_in[4];
    const float* b1     = (const float*)d_in[5];
    const float* W2     = (const float*)d_in[6];
    const float* b2     = (const float*)d_in[7];
    const float* W3     = (const float*)d_in[8];
    const float* b3     = (const float*)d_in[9];
    const float* Wr     = (const float*)d_in[10];
    const float* br     = (const float*)d_in[11];
    unsigned short* wf   = (unsigned short*)d_ws;
    float*          kbuf = (float*)((char*)d_ws + KBUF_BYTE);
    unsigned int*   flgs = (unsigned int*)((char*)d_ws + FLG_BYTE);

    size_t wcap = ws_size / 2;
    int wl = (wcap > (size_t)WF_TOTAL2) ? WF_TOTAL2 : (int)wcap;

    prep_kernel<<<(PREP_TOT + 255) / 256, 256, 0, stream>>>(W3, Wi, W1, W2, Wr,
                                                            wf, wl,
                                                            (unsigned long long)ws_size);
    cde_kernel<<<256, 1024, 0, stream>>>(coeffs, x_last, bi, b1, b2, b3, br, wf,
                                         kbuf, flgs, (float*)d_out);
}

// Round 19
// 1367.851 us; speedup vs baseline: 3.8511x; 3.8511x over previous
//
#include <hip/hip_runtime.h>
#include <math.h>

typedef __attribute__((ext_vector_type(8))) short v8s;
typedef __attribute__((ext_vector_type(4))) short v4s;
typedef __attribute__((ext_vector_type(2))) short v2s;
typedef __attribute__((ext_vector_type(4))) float v4f;

#define AP 136              // padded LDS row stride (shorts); 272 B rows keep 16B align
#define OFF_W3 0
#define OFF_WI 524288
#define OFF_W1 528384
#define OFF_W2 544768
#define OFF_WR 561152
#define LO     565248       // lo-residual region offset (shorts)
#define WF_TOTAL2 1130496   // hi+lo regions (shorts, 2.26 MB)
#define KBUF_BYTE 2260992   // float kbuf[16 bg][2 par][2048]  (256 KB)
#define FLG_BYTE  2523136   // uint flags[16 bg][16 tr] @ 16 B spacing (4 KB)
#define WS_END    2527232
#define PREP_W    565248    // weight-shuffle thread count
#define PREP_Z    33280     // zeroing threads: [KBUF_BYTE, WS_END) / 8
#define PREP_TOT  598528

static __device__ __forceinline__ float bf2f(unsigned short s){
    union { unsigned u; float f; } v; v.u = ((unsigned)s) << 16; return v.f;
}
static __device__ __forceinline__ unsigned short f2bf(float f){
    union { float ff; unsigned u; } v; v.ff = f;
    return (unsigned short)((v.u + 0x7FFFu + ((v.u >> 16) & 1u)) >> 16);
}
// triple split: v = h + m + l + eps, |eps| <= 2^-27 |v|
static __device__ __forceinline__ void split3(float v, unsigned short& h,
                                              unsigned short& m, unsigned short& l){
    h = f2bf(v);  float r1 = v - bf2f(h);
    m = f2bf(r1); float r2 = r1 - bf2f(m);
    l = f2bf(r2);
}
static __device__ __forceinline__ float softplus_f(float x){
    float t = __builtin_amdgcn_exp2f(x * 1.44269504088896341f);
    float r = 0.69314718055994531f * __builtin_amdgcn_logf(1.0f + t);
    return (x > 20.0f) ? x : r;
}
static __device__ __forceinline__ float tanh_f(float x){
    float xc = fminf(fmaxf(x, -9.0f), 9.0f);
    float t = __builtin_amdgcn_exp2f(xc * 2.8853900817779268f); // e^{2x}
    float d = t + 1.0f;
    float r = __builtin_amdgcn_rcpf(d);
    r = r * (2.0f - d * r);                                     // NR refine
    return (t - 1.0f) * r;
}

#define MFMA(acc, a, b) acc = __builtin_amdgcn_mfma_f32_16x16x32_bf16(a, b, acc, 0, 0, 0)

// ---------------------------------------------------------------------------
// Merged prep: fp32 weights -> bf16 hi+lo B-fragment layout, + zero the
// exchange region [KBUF_BYTE, WS_END).
// frag elem = W[kt*32 + (lane>>4)*8 + j][nt*16 + (lane&15)]
// ---------------------------------------------------------------------------
__global__ void prep_kernel(const float* __restrict__ W3,
                            const float* __restrict__ Wi,
                            const float* __restrict__ W1,
                            const float* __restrict__ W2,
                            const float* __restrict__ Wr,
                            unsigned short* __restrict__ dst,
                            int wlimit, unsigned long long wsbytes){
    int g = blockIdx.x * 256 + threadIdx.x;
    if (g >= PREP_TOT) return;
    if (g >= PREP_W){
        int t = g - PREP_W;
        unsigned long long byte = (unsigned long long)KBUF_BYTE + (unsigned long long)t * 8ull;
        if (t < PREP_Z && byte + 8ull <= wsbytes)
            *(unsigned long long*)((char*)dst + byte) = 0ull;
        return;
    }

    const float* W; int KT, N, t;
    if      (g < OFF_WI){ W = W3; KT = 4; N = 4096; t = g; }
    else if (g < OFF_W1){ W = Wi; KT = 1; N = 128;  t = g - OFF_WI; }
    else if (g < OFF_W2){ W = W1; KT = 4; N = 128;  t = g - OFF_W1; }
    else if (g < OFF_WR){ W = W2; KT = 4; N = 128;  t = g - OFF_W2; }
    else               { W = Wr; KT = 4; N = 32;   t = g - OFF_WR; }

    int j  = t & 7;
    int l  = (t >> 3) & 63;
    int t2 = t >> 9;
    int kt = t2 % KT;
    int nt = t2 / KT;
    int row = kt * 32 + (l >> 4) * 8 + j;
    int col = nt * 16 + (l & 15);
    float w = W[(size_t)row * N + col];
    unsigned short h = f2bf(w);
    if (g < wlimit)      dst[g]      = h;
    if (g + LO < wlimit) dst[g + LO] = f2bf(w - bf2f(h));
}

// ===========================================================================
// 512-thread variant (r16, proven 1389 us): wave wid -> tile wid, full r 0..3
// ===========================================================================
template<int KT, int MODE>
static __device__ __forceinline__ void gemm1_full(
    const unsigned short* __restrict__ wf, int wbase, int ntiles,
    const unsigned short* Ah, const unsigned short* Am, const unsigned short* Al,
    unsigned short* Aoh, unsigned short* Aom, unsigned short* Aol,
    float* zx,
    const float* __restrict__ bias_g,
    const float* __restrict__ xlast, float* __restrict__ outg, int bg)
{
    const int tid  = threadIdx.x;
    const int lane = tid & 63;
    const int wid  = tid >> 6;
    const int l15  = lane & 15;
    const int q    = lane >> 4;
    if (wid >= ntiles) return;
    const int nt = wid;

    v8s ah[KT], am[KT], al[KT];
#pragma unroll
    for (int kt = 0; kt < KT; ++kt){
        ah[kt] = *(const v8s*)&Ah[l15 * AP + kt * 32 + q * 8];
        am[kt] = *(const v8s*)&Am[l15 * AP + kt * 32 + q * 8];
        al[kt] = *(const v8s*)&Al[l15 * AP + kt * 32 + q * 8];
    }

    v4f acc = {0.f, 0.f, 0.f, 0.f};
#pragma unroll
    for (int kt = 0; kt < KT; ++kt){
        int o = wbase + ((nt * KT + kt) * 64 + lane) * 8;
        v8s bh = *(const v8s*)&wf[o];
        v8s bl = *(const v8s*)&wf[o + LO];
        MFMA(acc, ah[kt], bh); MFMA(acc, am[kt], bh); MFMA(acc, al[kt], bh);
        MFMA(acc, ah[kt], bl); MFMA(acc, am[kt], bl);
    }
    const int c0 = nt * 16 + l15;

    if (MODE == 0){
#pragma unroll
        for (int r = 0; r < 4; ++r){
            int b = q * 4 + r;
            zx[b * 128 + c0] = acc[r] + bias_g[c0];
        }
    } else if (MODE == 1){
#pragma unroll
        for (int r = 0; r < 4; ++r){
            int b = q * 4 + r;
            float v0 = softplus_f(acc[r] + bias_g[c0]);
            unsigned short h, m, l;
            split3(v0, h, m, l);
            Aoh[b*AP+c0] = h; Aom[b*AP+c0] = m; Aol[b*AP+c0] = l;
        }
    } else { // MODE 4
#pragma unroll
        for (int r = 0; r < 4; ++r){
            int b = q * 4 + r, gb = bg * 16 + b;
            outg[gb * 32 + c0] = acc[r] + bias_g[c0] + xlast[gb * 32 + c0];
        }
    }
}

__global__ __launch_bounds__(512, 1) void cde_kernel512(
    const float* __restrict__ coeffs,
    const float* __restrict__ x_last,
    const float* __restrict__ bi,
    const float* __restrict__ b1,
    const float* __restrict__ b2,
    const float* __restrict__ b3,
    const float* __restrict__ br,
    const unsigned short* __restrict__ wf,
    float* __restrict__ kbuf,
    unsigned int* __restrict__ flgs,
    float* __restrict__ outg)
{
    __shared__ unsigned short A0h[16*AP] __attribute__((aligned(16)));
    __shared__ unsigned short A0m[16*AP] __attribute__((aligned(16)));
    __shared__ unsigned short A0l[16*AP] __attribute__((aligned(16)));
    __shared__ unsigned short A1h[16*AP] __attribute__((aligned(16)));
    __shared__ unsigned short A1m[16*AP] __attribute__((aligned(16)));
    __shared__ unsigned short A1l[16*AP] __attribute__((aligned(16)));
    __shared__ unsigned short A2h[16*AP] __attribute__((aligned(16)));
    __shared__ unsigned short A2m[16*AP] __attribute__((aligned(16)));
    __shared__ unsigned short A2l[16*AP] __attribute__((aligned(16)));
    __shared__ float dval[512];
    __shared__ float zx[2048];

    const int tid  = threadIdx.x;
    const int lane = tid & 63;
    const int wid  = tid >> 6;          // 0..7
    const int l15  = lane & 15;
    const int q    = lane >> 4;
    const int bx   = blockIdx.x;
    const int bg   = (bx & 7) * 2 + (bx >> 7);   // team members share bx%8 (XCD)
    const int tr   = (bx >> 3) & 15;

    float*        kb0     = kbuf + bg * 4096;    // [par][2048]
    unsigned int* teamflg = flgs + bg * 64;      // 16 block flags @ 16 B
    unsigned int* myflag  = teamflg + tr * 4;

    for (int e = tid; e < 16*AP; e += 512){
        A0h[e]=0; A0m[e]=0; A0l[e]=0; A1h[e]=0; A1m[e]=0; A1l[e]=0;
        A2h[e]=0; A2m[e]=0; A2l[e]=0;
    }

    // reg-cached W3 slice frags; wave owns ONE pair p = wid (h = tr*8 + wid)
    v8s w3h[2][4], w3l[2][4];
    float b3v[2];
    {
        const int p = wid;
#pragma unroll
        for (int i = 0; i < 2; ++i){
            int ntg = tr * 16 + 2 * p + i;
#pragma unroll
            for (int kt = 0; kt < 4; ++kt){
                int o = ((ntg * 4 + kt) * 64 + lane) * 8;   // OFF_W3 = 0
                w3h[i][kt] = *(const v8s*)&wf[o];
                w3l[i][kt] = *(const v8s*)&wf[o + LO];
            }
        }
        int cg0 = tr * 256 + p * 32 + l15;
        b3v[0] = b3[cg0]; b3v[1] = b3[cg0 + 16];
    }

    const int arow = tid >> 5;
    const int acol = (tid & 31) * 4;
    const int e0r  = tid >> 5, e0c = tid & 31;

    // prologue: z0 = a0 @ Wi + bi
    {
        float v = coeffs[((size_t)(bg * 16 + e0r) * 64) * 128 + e0c];
        unsigned short h, m, l; split3(v, h, m, l);
        A0h[e0r*AP+e0c] = h; A0m[e0r*AP+e0c] = m; A0l[e0r*AP+e0c] = l;
    }
    __syncthreads();
    gemm1_full<1, 0>(wf, OFF_WI, 8, A0h, A0m, A0l, nullptr, nullptr, nullptr,
                     zx, bi, nullptr, nullptr, bg);
    __syncthreads();

    float zp[4], kap[4], k1p[4], k2p[4];
#pragma unroll
    for (int i = 0; i < 4; ++i){ zp[i] = zx[tid*4 + i]; kap[i]=0.f; k1p[i]=0.f; k2p[i]=0.f; }

    {
        size_t base = ((size_t)(bg * 16 + e0r) * 64 + 0) * 128;
        dval[tid] = coeffs[base + 32 + e0c];
        v4s vh, vm, vl;
#pragma unroll
        for (int i = 0; i < 4; ++i){
            unsigned short h, m, l; split3(zp[i], h, m, l);
            vh[i] = (short)h; vm[i] = (short)m; vl[i] = (short)l;
        }
        *(v4s*)&A0h[arow*AP + acol] = vh;
        *(v4s*)&A0m[arow*AP + acol] = vm;
        *(v4s*)&A0l[arow*AP + acol] = vl;
    }

    for (int st = 0; st < 256; ++st){
        const int sub = st & 3;
        __syncthreads();                       // (1)
        gemm1_full<4, 1>(wf, OFF_W1, 8, A0h, A0m, A0l, A1h, A1m, A1l,
                         nullptr, b1, nullptr, nullptr, bg);
        __syncthreads();                       // (2)
        gemm1_full<4, 1>(wf, OFF_W2, 8, A1h, A1m, A1l, A2h, A2m, A2l,
                         nullptr, b2, nullptr, nullptr, bg);
        __syncthreads();                       // (3)
        float* kbw = kb0 + (st & 1) * 2048;
        {
            v8s ah[4], am[4], al[4];
#pragma unroll
            for (int kt = 0; kt < 4; ++kt){
                ah[kt] = *(const v8s*)&A2h[l15*AP + kt*32 + q*8];
                am[kt] = *(const v8s*)&A2m[l15*AP + kt*32 + q*8];
                al[kt] = *(const v8s*)&A2l[l15*AP + kt*32 + q*8];
            }
            v4f acc0 = {0.f,0.f,0.f,0.f}, acc1 = {0.f,0.f,0.f,0.f};
#pragma unroll
            for (int kt = 0; kt < 4; ++kt){
                MFMA(acc0, ah[kt], w3h[0][kt]); MFMA(acc0, am[kt], w3h[0][kt]);
                MFMA(acc0, al[kt], w3h[0][kt]);
                MFMA(acc0, ah[kt], w3l[0][kt]); MFMA(acc0, am[kt], w3l[0][kt]);
                MFMA(acc1, ah[kt], w3h[1][kt]); MFMA(acc1, am[kt], w3h[1][kt]);
                MFMA(acc1, al[kt], w3h[1][kt]);
                MFMA(acc1, ah[kt], w3l[1][kt]); MFMA(acc1, am[kt], w3l[1][kt]);
            }
            float s4[4];
#pragma unroll
            for (int r = 0; r < 4; ++r){
                float u0 = acc0[r] + b3v[0];
                float u1 = acc1[r] + b3v[1];
                s4[r] = tanh_f(u0) * dval[(q*4 + r) * 32 + l15]
                      + tanh_f(u1) * dval[(q*4 + r) * 32 + 16 + l15];
            }
#pragma unroll
            for (int sm = 1; sm <= 8; sm <<= 1){
#pragma unroll
                for (int r = 0; r < 4; ++r) s4[r] += __shfl_xor(s4[r], sm);
            }
            if (l15 == 0){
#pragma unroll
                for (int r = 0; r < 4; ++r)
                    __hip_atomic_store(&kbw[(q*4 + r) * 128 + tr * 8 + wid], s4[r],
                                       __ATOMIC_RELAXED, __HIP_MEMORY_SCOPE_AGENT);
            }
            asm volatile("s_waitcnt vmcnt(0)" ::: "memory");
            __syncthreads();
            if (tid == 0)
                __hip_atomic_store(myflag, (unsigned)(st + 1),
                                   __ATOMIC_RELAXED, __HIP_MEMORY_SCOPE_AGENT);
        }

        const int stp1 = (st < 255) ? st + 1 : 255;
        const int sp   = stp1 >> 2, sb = stp1 & 3;
        int nidx; float nfrac;
        if      (sb == 0){ nidx = sp; nfrac = 0.f; }
        else if (sb == 1){ nidx = sp; nfrac = 1.f / 3.f; }
        else if (sb == 2){ nidx = sp; nfrac = 2.f / 3.f; }
        else { nidx = (sp < 63) ? sp + 1 : 63; nfrac = (sp < 63) ? 0.f : 1.f; }
        float cb0, cc0, cd0;
        {
            size_t base = ((size_t)(bg * 16 + e0r) * 64 + nidx) * 128;
            cb0 = coeffs[base + 32 + e0c];
            cc0 = coeffs[base + 64 + e0c];
            cd0 = coeffs[base + 96 + e0c];
        }

        {
            const unsigned tgt = (unsigned)(st + 1);
            const unsigned int* fp = &teamflg[((tid & 31) >> 1) * 4];
            unsigned it = 0;
            while (__hip_atomic_load(fp, __ATOMIC_RELAXED,
                                     __HIP_MEMORY_SCOPE_AGENT) < tgt
                   && ++it < (1u << 22))
                __builtin_amdgcn_s_sleep(1);
        }

        float kv[4];
#pragma unroll
        for (int i = 0; i < 2; ++i){
            union { unsigned long long u; float f[2]; } pk;
            pk.u = __hip_atomic_load((const unsigned long long*)&kbw[tid*4 + 2*i],
                                     __ATOMIC_RELAXED, __HIP_MEMORY_SCOPE_AGENT);
            kv[2*i] = pk.f[0]; kv[2*i+1] = pk.f[1];
        }
#pragma unroll
        for (int i = 0; i < 4; ++i){
            float k = kv[i];
            if      (sub == 0){ k1p[i] = k; kap[i] = zp[i] + k * (1.f/3.f); }
            else if (sub == 1){ k2p[i] = k; kap[i] = zp[i] + (k - k1p[i] * (1.f/3.f)); }
            else if (sub == 2){ kap[i] = zp[i] + (k1p[i] - k2p[i] + k); }
            else { zp[i] = zp[i] + (6.f*k2p[i] - 2.f*k1p[i]
                                    + 3.f*(kap[i] - zp[i]) + k) * 0.125f; }
        }

        dval[tid] = cb0 + (cc0 + cd0 * nfrac) * nfrac;
        {
            const int nsub = stp1 & 3;
            v4s vh, vm, vl;
#pragma unroll
            for (int i = 0; i < 4; ++i){
                float v = (nsub == 0) ? zp[i] : kap[i];
                unsigned short h, m, l; split3(v, h, m, l);
                vh[i] = (short)h; vm[i] = (short)m; vl[i] = (short)l;
            }
            *(v4s*)&A0h[arow*AP + acol] = vh;
            *(v4s*)&A0m[arow*AP + acol] = vm;
            *(v4s*)&A0l[arow*AP + acol] = vl;
        }
    }

    {
        v4s vh, vm, vl;
#pragma unroll
        for (int i = 0; i < 4; ++i){
            unsigned short h, m, l; split3(zp[i], h, m, l);
            vh[i] = (short)h; vm[i] = (short)m; vl[i] = (short)l;
        }
        *(v4s*)&A0h[arow*AP + acol] = vh;
        *(v4s*)&A0m[arow*AP + acol] = vm;
        *(v4s*)&A0l[arow*AP + acol] = vl;
    }
    __syncthreads();
    gemm1_full<4, 4>(wf, OFF_WR, 2, A0h, A0m, A0l, nullptr, nullptr, nullptr,
                     nullptr, br, x_last, outg, bg);
}

// ===========================================================================
// 1024-thread variant (r17 structure): wave pair (w, w+8) duplicates MFMA on
// tile w&7 and r-splits the epilogue. amdgpu_waves_per_eu(4,4) caps the
// allocator's occupancy target at 4 waves/EU -> 128 VGPRs (fix for the
// 64-VGPR spill cliff seen in r17/r18).
// ===========================================================================
template<int KT, int MODE>
static __device__ __forceinline__ void gemm1_split(
    const unsigned short* __restrict__ wf, int wbase, int ntiles,
    const unsigned short* Ah, const unsigned short* Am, const unsigned short* Al,
    unsigned short* Aoh, unsigned short* Aom, unsigned short* Aol,
    float* zx,
    const float* __restrict__ bias_g,
    const float* __restrict__ xlast, float* __restrict__ outg, int bg)
{
    const int tid  = threadIdx.x;
    const int lane = tid & 63;
    const int wid  = tid >> 6;
    const int l15  = lane & 15;
    const int q    = lane >> 4;
    const int nt   = wid & 7;
    const int rlo  = (wid >> 3) * 2;
    if (nt >= ntiles) return;

    v8s ah[KT], am[KT], al[KT];
#pragma unroll
    for (int kt = 0; kt < KT; ++kt){
        ah[kt] = *(const v8s*)&Ah[l15 * AP + kt * 32 + q * 8];
        am[kt] = *(const v8s*)&Am[l15 * AP + kt * 32 + q * 8];
        al[kt] = *(const v8s*)&Al[l15 * AP + kt * 32 + q * 8];
    }

    v4f acc = {0.f, 0.f, 0.f, 0.f};
#pragma unroll
    for (int kt = 0; kt < KT; ++kt){
        int o = wbase + ((nt * KT + kt) * 64 + lane) * 8;
        v8s bh = *(const v8s*)&wf[o];
        v8s bl = *(const v8s*)&wf[o + LO];
        MFMA(acc, ah[kt], bh); MFMA(acc, am[kt], bh); MFMA(acc, al[kt], bh);
        MFMA(acc, ah[kt], bl); MFMA(acc, am[kt], bl);
    }
    const int c0 = nt * 16 + l15;

    if (MODE == 0){
#pragma unroll
        for (int rr = 0; rr < 2; ++rr){
            int r = rlo + rr, b = q * 4 + r;
            zx[b * 128 + c0] = acc[r] + bias_g[c0];
        }
    } else if (MODE == 1){
#pragma unroll
        for (int rr = 0; rr < 2; ++rr){
            int r = rlo + rr, b = q * 4 + r;
            float v0 = softplus_f(acc[r] + bias_g[c0]);
            unsigned short h, m, l;
            split3(v0, h, m, l);
            Aoh[b*AP+c0] = h; Aom[b*AP+c0] = m; Aol[b*AP+c0] = l;
        }
    } else { // MODE 4
#pragma unroll
        for (int rr = 0; rr < 2; ++rr){
            int r = rlo + rr, b = q * 4 + r, gb = bg * 16 + b;
            outg[gb * 32 + c0] = acc[r] + bias_g[c0] + xlast[gb * 32 + c0];
        }
    }
}

__global__ __launch_bounds__(1024)
__attribute__((amdgpu_waves_per_eu(4, 4)))
void cde_kernel1024(
    const float* __restrict__ coeffs,
    const float* __restrict__ x_last,
    const float* __restrict__ bi,
    const float* __restrict__ b1,
    const float* __restrict__ b2,
    const float* __restrict__ b3,
    const float* __restrict__ br,
    const unsigned short* __restrict__ wf,
    float* __restrict__ kbuf,
    unsigned int* __restrict__ flgs,
    float* __restrict__ outg)
{
    __shared__ unsigned short A0h[16*AP] __attribute__((aligned(16)));
    __shared__ unsigned short A0m[16*AP] __attribute__((aligned(16)));
    __shared__ unsigned short A0l[16*AP] __attribute__((aligned(16)));
    __shared__ unsigned short A1h[16*AP] __attribute__((aligned(16)));
    __shared__ unsigned short A1m[16*AP] __attribute__((aligned(16)));
    __shared__ unsigned short A1l[16*AP] __attribute__((aligned(16)));
    __shared__ unsigned short A2h[16*AP] __attribute__((aligned(16)));
    __shared__ unsigned short A2m[16*AP] __attribute__((aligned(16)));
    __shared__ unsigned short A2l[16*AP] __attribute__((aligned(16)));
    __shared__ float dval[512];
    __shared__ float zx[2048];

    const int tid  = threadIdx.x;
    const int lane = tid & 63;
    const int wid  = tid >> 6;          // 0..15
    const int l15  = lane & 15;
    const int q    = lane >> 4;
    const int wid8 = wid & 7;
    const int rlo  = (wid >> 3) * 2;
    const int bx   = blockIdx.x;
    const int bg   = (bx & 7) * 2 + (bx >> 7);
    const int tr   = (bx >> 3) & 15;

    float*        kb0     = kbuf + bg * 4096;
    unsigned int* teamflg = flgs + bg * 64;
    unsigned int* myflag  = teamflg + tr * 4;

    for (int e = tid; e < 16*AP; e += 1024){
        A0h[e]=0; A0m[e]=0; A0l[e]=0; A1h[e]=0; A1m[e]=0; A1l[e]=0;
        A2h[e]=0; A2m[e]=0; A2l[e]=0;
    }

    v8s w3h[2][4], w3l[2][4];
    float b3v[2];
    {
        const int p = wid8;
#pragma unroll
        for (int i = 0; i < 2; ++i){
            int ntg = tr * 16 + 2 * p + i;
#pragma unroll
            for (int kt = 0; kt < 4; ++kt){
                int o = ((ntg * 4 + kt) * 64 + lane) * 8;
                w3h[i][kt] = *(const v8s*)&wf[o];
                w3l[i][kt] = *(const v8s*)&wf[o + LO];
            }
        }
        int cg0 = tr * 256 + p * 32 + l15;
        b3v[0] = b3[cg0]; b3v[1] = b3[cg0 + 16];
    }

    const int arow = tid >> 6;
    const int acol = (tid & 63) * 2;
    const int e0r  = (tid >> 5) & 15, e0c = tid & 31;

    if (tid < 512){
        float v = coeffs[((size_t)(bg * 16 + e0r) * 64) * 128 + e0c];
        unsigned short h, m, l; split3(v, h, m, l);
        A0h[e0r*AP+e0c] = h; A0m[e0r*AP+e0c] = m; A0l[e0r*AP+e0c] = l;
    }
    __syncthreads();
    gemm1_split<1, 0>(wf, OFF_WI, 8, A0h, A0m, A0l, nullptr, nullptr, nullptr,
                      zx, bi, nullptr, nullptr, bg);
    __syncthreads();

    float zp[2], kap[2], k1p[2], k2p[2];
#pragma unroll
    for (int i = 0; i < 2; ++i){ zp[i] = zx[tid*2 + i]; kap[i]=0.f; k1p[i]=0.f; k2p[i]=0.f; }

    {
        if (tid < 512){
            size_t base = ((size_t)(bg * 16 + e0r) * 64 + 0) * 128;
            dval[tid] = coeffs[base + 32 + e0c];
        }
        v2s vh, vm, vl;
#pragma unroll
        for (int i = 0; i < 2; ++i){
            unsigned short h, m, l; split3(zp[i], h, m, l);
            vh[i] = (short)h; vm[i] = (short)m; vl[i] = (short)l;
        }
        *(v2s*)&A0h[arow*AP + acol] = vh;
        *(v2s*)&A0m[arow*AP + acol] = vm;
        *(v2s*)&A0l[arow*AP + acol] = vl;
    }

    for (int st = 0; st < 256; ++st){
        const int sub = st & 3;
        __syncthreads();
        gemm1_split<4, 1>(wf, OFF_W1, 8, A0h, A0m, A0l, A1h, A1m, A1l,
                          nullptr, b1, nullptr, nullptr, bg);
        __syncthreads();
        gemm1_split<4, 1>(wf, OFF_W2, 8, A1h, A1m, A1l, A2h, A2m, A2l,
                          nullptr, b2, nullptr, nullptr, bg);
        __syncthreads();
        float* kbw = kb0 + (st & 1) * 2048;
        {
            v8s ah[4], am[4], al[4];
#pragma unroll
            for (int kt = 0; kt < 4; ++kt){
                ah[kt] = *(const v8s*)&A2h[l15*AP + kt*32 + q*8];
                am[kt] = *(const v8s*)&A2m[l15*AP + kt*32 + q*8];
                al[kt] = *(const v8s*)&A2l[l15*AP + kt*32 + q*8];
            }
            v4f acc0 = {0.f,0.f,0.f,0.f}, acc1 = {0.f,0.f,0.f,0.f};
#pragma unroll
            for (int kt = 0; kt < 4; ++kt){
                MFMA(acc0, ah[kt], w3h[0][kt]); MFMA(acc0, am[kt], w3h[0][kt]);
                MFMA(acc0, al[kt], w3h[0][kt]);
                MFMA(acc0, ah[kt], w3l[0][kt]); MFMA(acc0, am[kt], w3l[0][kt]);
                MFMA(acc1, ah[kt], w3h[1][kt]); MFMA(acc1, am[kt], w3h[1][kt]);
                MFMA(acc1, al[kt], w3h[1][kt]);
                MFMA(acc1, ah[kt], w3l[1][kt]); MFMA(acc1, am[kt], w3l[1][kt]);
            }
            float s4[2];
#pragma unroll
            for (int rr = 0; rr < 2; ++rr){
                int r = rlo + rr;
                float u0 = acc0[r] + b3v[0];
                float u1 = acc1[r] + b3v[1];
                s4[rr] = tanh_f(u0) * dval[(q*4 + r) * 32 + l15]
                       + tanh_f(u1) * dval[(q*4 + r) * 32 + 16 + l15];
            }
#pragma unroll
            for (int sm = 1; sm <= 8; sm <<= 1){
#pragma unroll
                for (int rr = 0; rr < 2; ++rr) s4[rr] += __shfl_xor(s4[rr], sm);
            }
            if (l15 == 0){
#pragma unroll
                for (int rr = 0; rr < 2; ++rr){
                    int r = rlo + rr;
                    __hip_atomic_store(&kbw[(q*4 + r) * 128 + tr * 8 + wid8], s4[rr],
                                       __ATOMIC_RELAXED, __HIP_MEMORY_SCOPE_AGENT);
                }
            }
            asm volatile("s_waitcnt vmcnt(0)" ::: "memory");
            __syncthreads();
            if (tid == 0)
                __hip_atomic_store(myflag, (unsigned)(st + 1),
                                   __ATOMIC_RELAXED, __HIP_MEMORY_SCOPE_AGENT);
        }

        const int stp1 = (st < 255) ? st + 1 : 255;
        const int sp   = stp1 >> 2, sb = stp1 & 3;
        int nidx; float nfrac;
        if      (sb == 0){ nidx = sp; nfrac = 0.f; }
        else if (sb == 1){ nidx = sp; nfrac = 1.f / 3.f; }
        else if (sb == 2){ nidx = sp; nfrac = 2.f / 3.f; }
        else { nidx = (sp < 63) ? sp + 1 : 63; nfrac = (sp < 63) ? 0.f : 1.f; }
        float cb0 = 0.f, cc0 = 0.f, cd0 = 0.f;
        if (tid < 512){
            size_t base = ((size_t)(bg * 16 + e0r) * 64 + nidx) * 128;
            cb0 = coeffs[base + 32 + e0c];
            cc0 = coeffs[base + 64 + e0c];
            cd0 = coeffs[base + 96 + e0c];
        }

        {
            const unsigned tgt = (unsigned)(st + 1);
            const unsigned int* fp = &teamflg[((tid & 63) >> 2) * 4];
            unsigned it = 0;
            while (__hip_atomic_load(fp, __ATOMIC_RELAXED,
                                     __HIP_MEMORY_SCOPE_AGENT) < tgt
                   && ++it < (1u << 22))
                __builtin_amdgcn_s_sleep(1);
        }

        float kv[2];
        {
            union { unsigned long long u; float f[2]; } pk;
            pk.u = __hip_atomic_load((const unsigned long long*)&kbw[tid*2],
                                     __ATOMIC_RELAXED, __HIP_MEMORY_SCOPE_AGENT);
            kv[0] = pk.f[0]; kv[1] = pk.f[1];
        }
#pragma unroll
        for (int i = 0; i < 2; ++i){
            float k = kv[i];
            if      (sub == 0){ k1p[i] = k; kap[i] = zp[i] + k * (1.f/3.f); }
            else if (sub == 1){ k2p[i] = k; kap[i] = zp[i] + (k - k1p[i] * (1.f/3.f)); }
            else if (sub == 2){ kap[i] = zp[i] + (k1p[i] - k2p[i] + k); }
            else { zp[i] = zp[i] + (6.f*k2p[i] - 2.f*k1p[i]
                                    + 3.f*(kap[i] - zp[i]) + k) * 0.125f; }
        }

        if (tid < 512)
            dval[tid] = cb0 + (cc0 + cd0 * nfrac) * nfrac;
        {
            const int nsub = stp1 & 3;
            v2s vh, vm, vl;
#pragma unroll
            for (int i = 0; i < 2; ++i){
                float v = (nsub == 0) ? zp[i] : kap[i];
                unsigned short h, m, l; split3(v, h, m, l);
                vh[i] = (short)h; vm[i] = (short)m; vl[i] = (short)l;
            }
            *(v2s*)&A0h[arow*AP + acol] = vh;
            *(v2s*)&A0m[arow*AP + acol] = vm;
            *(v2s*)&A0l[arow*AP + acol] = vl;
        }
    }

    {
        v2s vh, vm, vl;
#pragma unroll
        for (int i = 0; i < 2; ++i){
            unsigned short h, m, l; split3(zp[i], h, m, l);
            vh[i] = (short)h; vm[i] = (short)m; vl[i] = (short)l;
        }
        *(v2s*)&A0h[arow*AP + acol] = vh;
        *(v2s*)&A0m[arow*AP + acol] = vm;
        *(v2s*)&A0l[arow*AP + acol] = vl;
    }
    __syncthreads();
    gemm1_split<4, 4>(wf, OFF_WR, 2, A0h, A0m, A0l, nullptr, nullptr, nullptr,
                      nullptr, br, x_last, outg, bg);
}

extern "C" void kernel_launch(void* const* d_in, const int* in_sizes, int n_in,
                              void* d_out, int out_size, void* d_ws, size_t ws_size,
                              hipStream_t stream)
{
    const float* coeffs = (const float*)d_in[0];
    const float* x_last = (const float*)d_in[1];
    const float* Wi     = (const float*)d_in[2];
    const float* bi     = (const float*)d_in[3];
    const float* W1     = (const float*)d_in[4];
    const float* b1     = (const float*)d_in[5];
    const float* W2     = (const float*)d_in[6];
    const float* b2     = (const float*)d_in[7];
    const float* W3     = (const float*)d_in[8];
    const float* b3     = (const float*)d_in[9];
    const float* Wr     = (const float*)d_in[10];
    const float* br     = (const float*)d_in[11];
    unsigned short* wf   = (unsigned short*)d_ws;
    float*          kbuf = (float*)((char*)d_ws + KBUF_BYTE);
    unsigned int*   flgs = (unsigned int*)((char*)d_ws + FLG_BYTE);

    size_t wcap = ws_size / 2;
    int wl = (wcap > (size_t)WF_TOTAL2) ? WF_TOTAL2 : (int)wcap;

    prep_kernel<<<(PREP_TOT + 255) / 256, 256, 0, stream>>>(W3, Wi, W1, W2, Wr,
                                                            wf, wl,
                                                            (unsigned long long)ws_size);

    // Guard: only launch the 1024-thread kernel if the compiler actually got
    // >=96 VGPRs with no spill scratch (r17/r18 regressed at 64 VGPR + spill).
    // Host-side query; not a stream op -> graph-capture safe, same every call.
    bool use1024 = false;
    hipFuncAttributes attr{};
    if (hipFuncGetAttributes(&attr, reinterpret_cast<const void*>(cde_kernel1024))
        == hipSuccess)
        use1024 = (attr.numRegs >= 96) && (attr.localSizeBytes == 0);

    if (use1024)
        cde_kernel1024<<<256, 1024, 0, stream>>>(coeffs, x_last, bi, b1, b2, b3,
                                                 br, wf, kbuf, flgs, (float*)d_out);
    else
        cde_kernel512<<<256, 512, 0, stream>>>(coeffs, x_last, bi, b1, b2, b3,
                                               br, wf, kbuf, flgs, (float*)d_out);
}